// Round 6
// baseline (535.365 us; speedup 1.0000x reference)
//
#include <hip/hip_runtime.h>

#define LOG2E 1.4426950408889634f
#define GRID 256
#define MAGIC 0x13579BDFu

// fast sigmoid: rcp approx ~1e-6 rel; tolerance headroom is ~250x
__device__ __forceinline__ float fsig(float z) {
    return __builtin_amdgcn_rcpf(1.0f + exp2f(-z * LOG2E));
}

// ---------------------------------------------------------------------------
// Device-scope grid barrier (round-5-proven pattern). Slot j at cnt[16+16j].
// ---------------------------------------------------------------------------
__device__ __forceinline__ void grid_bar(unsigned* cnt, int slot) {
    __syncthreads();
    if (threadIdx.x == 0) {
        __threadfence();
        unsigned* c = &cnt[16 + slot * 16];
        atomicAdd(c, 1u);
        while (atomicAdd(c, 0u) < (unsigned)GRID) __builtin_amdgcn_s_sleep(1);
        __threadfence();
    }
    __syncthreads();
}

// ---------------------------------------------------------------------------
// conv3x3(roll(fb)*fade) + damping MLP at one pixel, fb in global (L2).
// ---------------------------------------------------------------------------
__device__ __forceinline__ void conv_damp(
    const float4* __restrict__ src, int yq, int xq, int ys, int xs,
    const float* fe, const float4 wr[9][4],
    const float4 d1w0, const float4 d1w1, const float2 d1b, const float4 d2p[4],
    float rv[4])
{
    float r[4] = { d2p[0].w, d2p[1].w, d2p[2].w, d2p[3].w };   // conv bias (fbb)
    #pragma unroll
    for (int a = 0; a < 3; ++a) {
        int yy = yq - 1 + a;
        float fy = fe[yy + 1];                       // 0 outside image -> zero pad
        const float4* rowp = src + (((yy - ys) & 63) << 6);
        #pragma unroll
        for (int qq = 0; qq < 3; ++qq) {
            int xt = xq - 1 + qq;
            float f = fy * fe[xt + 1];
            float4 v = rowp[(xt - xs) & 63];
            float s0 = v.x * f, s1 = v.y * f, s2 = v.z * f, s3 = v.w * f;
            #pragma unroll
            for (int co = 0; co < 4; ++co) {
                float4 w = wr[a * 3 + qq][co];
                r[co] = fmaf(w.x, s0, fmaf(w.y, s1, fmaf(w.z, s2, fmaf(w.w, s3, r[co]))));
            }
        }
    }
    float z0 = fmaf(d1w0.x, r[0], fmaf(d1w0.y, r[1], fmaf(d1w0.z, r[2], fmaf(d1w0.w, r[3], d1b.x))));
    float z1 = fmaf(d1w1.x, r[0], fmaf(d1w1.y, r[1], fmaf(d1w1.z, r[2], fmaf(d1w1.w, r[3], d1b.y))));
    float h0 = z0 * fsig(z0);
    float h1 = z1 * fsig(z1);
    #pragma unroll
    for (int c = 0; c < 4; ++c) {
        float dm = fsig(fmaf(d2p[c].x, h0, fmaf(d2p[c].y, h1, d2p[c].z)));
        rv[c] = r[c] * dm;
    }
}

// ---------------------------------------------------------------------------
// Single fused kernel: reverb -> attention -> proj+blur -> final.
// Grid 256 x 512, all blocks co-resident (52KB LDS, VGPR<=256 -> >=2 blk/CU
// capacity). 19 device-scope barriers; boot flag replaces the init launch.
// ---------------------------------------------------------------------------
__global__ __launch_bounds__(512) void fused_kernel(
    const float* __restrict__ x, const float* __restrict__ rw, const float* __restrict__ dl,
    const float* __restrict__ fbw, const float* __restrict__ fbb,
    const float* __restrict__ d1wg, const float* __restrict__ d1bg,
    const float* __restrict__ d2wg, const float* __restrict__ d2bg,
    const float* __restrict__ aiw, const float* __restrict__ aib,
    const float* __restrict__ aow, const float* __restrict__ aob,
    const float* __restrict__ swg, const float* __restrict__ sbg,
    const float* __restrict__ owg, const float* __restrict__ obg,
    float4* __restrict__ fbA, float4* __restrict__ fbB,
    float4* __restrict__ ws_wet, float* __restrict__ o_buf, float* __restrict__ blur_buf,
    unsigned* __restrict__ cnt, float* __restrict__ out)
{
    __shared__ float4 kvs4[2048];     // 32 KB: (k,v) pairs for 4096 keys
    __shared__ float2 part[2048];     // 16 KB: [kg][row_local]
    __shared__ float fe[66];
    __shared__ float4 wvsL[36];
    __shared__ float s_rw[16], s_dl[16];
    __shared__ float4 s_mlp[7];
    __shared__ float s_sw[288], s_ow[48], s_sb[8], s_ob[4];
    __shared__ float redmx[8], redmn[8];

    const int tid = threadIdx.x;
    const int blk = blockIdx.x;

    // ---- stage LDS statics (all blocks) ----
    if (tid < 66) {
        float f = 0.0f;
        if (tid >= 1 && tid <= 64) {
            int j = tid - 1;
            f = 1.0f;
            if (j < 4) f = 0.6f + (0.4f / 3.0f) * j;
            else if (j >= 60) f = 0.6f + (0.4f / 3.0f) * (63 - j);
        }
        fe[tid] = f;
    }
    if (tid >= 128 && tid < 164) {
        int t2 = tid - 128, n = t2 >> 2, co = t2 & 3;
        wvsL[t2] = make_float4(fbw[(co * 4 + 0) * 9 + n], fbw[(co * 4 + 1) * 9 + n],
                               fbw[(co * 4 + 2) * 9 + n], fbw[(co * 4 + 3) * 9 + n]);
    }
    if (tid >= 192 && tid < 208) s_rw[tid - 192] = rw[tid - 192];
    if (tid >= 224 && tid < 240) s_dl[tid - 224] = dl[tid - 224];
    if (tid == 256) {
        s_mlp[0] = make_float4(d1wg[0], d1wg[1], d1wg[2], d1wg[3]);
        s_mlp[1] = make_float4(d1wg[4], d1wg[5], d1wg[6], d1wg[7]);
        s_mlp[2] = make_float4(d1bg[0], d1bg[1], 0.0f, 0.0f);
        for (int c = 0; c < 4; ++c)
            s_mlp[3 + c] = make_float4(d2wg[c * 2], d2wg[c * 2 + 1], d2bg[c], fbb[c]);
    }
    if (tid >= 336 && tid < 384) s_ow[tid - 336] = owg[tid - 336];
    if (tid >= 384 && tid < 392) s_sb[tid - 384] = sbg[tid - 384];
    if (tid >= 392 && tid < 396) s_ob[tid - 392] = obg[tid - 392];
    for (int j = tid; j < 288; j += 512) s_sw[j] = swg[j];

    // ---- boot: block 0 zeros barrier slots, raises flag; others wait ----
    if (blk == 0) {
        for (int i = tid; i < 304; i += 512) cnt[16 + i] = 0u;
        __syncthreads();                       // zeroing + LDS statics done
        if (tid == 0) { __threadfence(); atomicExch(&cnt[0], MAGIC); }
    } else {
        __syncthreads();                       // LDS statics done
        if (tid == 0) {
            while (atomicAdd(&cnt[0], 0u) != MAGIC) __builtin_amdgcn_s_sleep(1);
        }
        __syncthreads();
    }

    // =====================================================================
    // Stage 1: reverb. Block owns 64 consecutive pixels (one image row),
    // wave 0 does the work (1 px/lane); other waves only hit barriers.
    // =====================================================================
    const int p   = (blk << 6) + (tid & 63);
    const int bb_ = p >> 12;
    const int s_  = p & 4095;
    const int y0  = s_ >> 6;
    const int xx  = s_ & 63;
    const float4* Ab = fbA + (bb_ << 12);
    const float4* Bb = fbB + (bb_ << 12);

    float4 wr[9][4];
    float4 d1w0, d1w1, d2p[4];
    float2 d1b;
    float4 fbv;
    float acc0 = 0.0f, acc1 = 0.0f, acc2 = 0.0f, acc3 = 0.0f;

    if (tid < 64) {
        #pragma unroll
        for (int n = 0; n < 9; ++n)
            #pragma unroll
            for (int co = 0; co < 4; ++co) wr[n][co] = wvsL[n * 4 + co];
        d1w0 = s_mlp[0]; d1w1 = s_mlp[1];
        d1b = make_float2(s_mlp[2].x, s_mlp[2].y);
        d2p[0] = s_mlp[3]; d2p[1] = s_mlp[4]; d2p[2] = s_mlp[5]; d2p[3] = s_mlp[6];

        fbv.x = 0.1f * x[((bb_ * 4 + 0) << 12) + s_];
        fbv.y = 0.1f * x[((bb_ * 4 + 1) << 12) + s_];
        fbv.z = 0.1f * x[((bb_ * 4 + 2) << 12) + s_];
        fbv.w = 0.1f * x[((bb_ * 4 + 3) << 12) + s_];
        ((float4*)Ab)[s_] = fbv;
    }
    grid_bar(cnt, 0);

    float decay = 1.0f;
    for (int i = 0; i < 16; ++i) {
        if (tid < 64) {
            const float4* src = (i & 1) ? Bb : Ab;
            float4* dst = (float4*)((i & 1) ? Ab : Bb);
            float d = s_dl[i];
            int ys  = ((int)(3.0f * d)) & 63;
            int xs  = ((int)(6.0f * d)) & 63;
            int ys2 = ((int)(1.5f * d)) & 63;
            int xs2 = ((int)(3.0f * d)) & 63;
            float wgt = fsig(s_rw[i]) * decay * 3.0f;

            float rv[4];
            conv_damp(src, y0, xx, ys, xs, fe, wr, d1w0, d1w1, d1b, d2p, rv);
            acc0 = fmaf(rv[0], wgt, acc0);
            acc1 = fmaf(rv[1], wgt, acc1);
            acc2 = fmaf(rv[2], wgt, acc2);
            acc3 = fmaf(rv[3], wgt, acc3);
            float4 fnew = make_float4(fbv.x + 0.24f * rv[0], fbv.y + 0.24f * rv[1],
                                      fbv.z + 0.24f * rv[2], fbv.w + 0.24f * rv[3]);
            if (i > 0) {
                int yr = (y0 - ys2) & 63, xr = (xx - xs2) & 63;
                float rvr[4];
                conv_damp(src, yr, xr, ys, xs, fe, wr, d1w0, d1w1, d1b, d2p, rvr);
                float4 fr = src[(yr << 6) + xr];
                float f = 0.08f * fe[y0 + 1] * fe[xx + 1];
                fnew.x = fmaf(f, fmaf(0.24f, rvr[0], fr.x), fnew.x);
                fnew.y = fmaf(f, fmaf(0.24f, rvr[1], fr.y), fnew.y);
                fnew.z = fmaf(f, fmaf(0.24f, rvr[2], fr.z), fnew.z);
                fnew.w = fmaf(f, fmaf(0.24f, rvr[3], fr.w), fnew.w);
            }
            dst[s_] = fnew;
            fbv = fnew;
        }
        decay *= 0.8f;
        if (i < 15) grid_bar(cnt, 1 + i);
    }
    if (tid < 64) ws_wet[p] = make_float4(acc0, acc1, acc2, acc3);
    grid_bar(cnt, 16);

    // =====================================================================
    // Stage 2: attention (head_dim=1). Block = (b,h, 256-row chunk).
    // 512 thr = 64 row-slots (4 rows each) x 8 key-groups (512 keys each).
    // =====================================================================
    {
        const int bh = blk >> 4;
        const int ab = bh >> 2, ah = bh & 3;
        const int qc = blk & 15;

        float wq[4], wk[4], wv[4];
        #pragma unroll
        for (int c = 0; c < 4; ++c) {
            wq[c] = aiw[ah * 4 + c];
            wk[c] = aiw[(4 + ah) * 4 + c];
            wv[c] = aiw[(8 + ah) * 4 + c];
        }
        const float bq = aib[ah], bk = aib[4 + ah], bv = aib[8 + ah];

        float2* kvs = (float2*)kvs4;
        float lmax = -1e30f, lmin = 1e30f;
        for (int s = tid; s < 4096; s += 512) {
            float4 w4 = ws_wet[(ab << 12) + s];
            float k = wk[0] * w4.x + wk[1] * w4.y + wk[2] * w4.z + wk[3] * w4.w + bk;
            float v = wv[0] * w4.x + wv[1] * w4.y + wv[2] * w4.z + wv[3] * w4.w + bv;
            kvs[s] = make_float2(k, v);
            lmax = fmaxf(lmax, k); lmin = fminf(lmin, k);
        }
        #pragma unroll
        for (int off = 32; off > 0; off >>= 1) {
            lmax = fmaxf(lmax, __shfl_xor(lmax, off));
            lmin = fminf(lmin, __shfl_xor(lmin, off));
        }
        if ((tid & 63) == 0) { redmx[tid >> 6] = lmax; redmn[tid >> 6] = lmin; }
        __syncthreads();
        float kmax = redmx[0], kmin = redmn[0];
        #pragma unroll
        for (int w = 1; w < 8; ++w) { kmax = fmaxf(kmax, redmx[w]); kmin = fminf(kmin, redmn[w]); }

        const int rs = tid & 63;
        const int kg = tid >> 6;
        float qL[4], mL[4];
        #pragma unroll
        for (int rr = 0; rr < 4; ++rr) {
            int row = (qc << 8) + (rs << 2) + rr;
            float4 w4 = ws_wet[(ab << 12) + row];
            float q = wq[0] * w4.x + wq[1] * w4.y + wq[2] * w4.z + wq[3] * w4.w + bq;
            float m = (q >= 0.0f) ? q * kmax : q * kmin;   // exact row max (hd=1)
            qL[rr] = q * LOG2E; mL[rr] = m * LOG2E;
        }

        float den[4] = {0, 0, 0, 0}, num[4] = {0, 0, 0, 0};
        const int j0 = kg << 8;        // 256 float4 = 512 keys per group
        #pragma unroll 2
        for (int j = j0; j < j0 + 256; ++j) {
            float4 t = kvs4[j];
            #pragma unroll
            for (int rr = 0; rr < 4; ++rr) {
                float e0 = exp2f(fmaf(qL[rr], t.x, -mL[rr]));
                float e1 = exp2f(fmaf(qL[rr], t.z, -mL[rr]));
                den[rr] += e0 + e1;
                num[rr] = fmaf(e0, t.y, fmaf(e1, t.w, num[rr]));
            }
        }
        #pragma unroll
        for (int rr = 0; rr < 4; ++rr)
            part[(kg << 8) + (rs << 2) + rr] = make_float2(den[rr], num[rr]);
        __syncthreads();
        if (tid < 256) {
            float dd = 0.0f, nn = 0.0f;
            #pragma unroll
            for (int g = 0; g < 8; ++g) {
                float2 pp = part[(g << 8) + tid];
                dd += pp.x; nn += pp.y;
            }
            int row = (qc << 8) + tid;
            o_buf[(((ab << 12) + row) << 2) + ah] = nn * __builtin_amdgcn_rcpf(dd);
        }
    }
    grid_bar(cnt, 17);

    // =====================================================================
    // Stage 3: attn out-projection + 3x3 box blur (on the fly, zero pad).
    // Block = (plane bc, 4-row slab). Threads 0..255: 1 px each.
    // =====================================================================
    {
        const int bc = blk >> 4;
        const int sub = blk & 15;
        const int pb = bc >> 2, pc = bc & 3;
        const float w0 = aow[pc * 4], w1 = aow[pc * 4 + 1],
                    w2 = aow[pc * 4 + 2], w3 = aow[pc * 4 + 3];
        const float bbp = aob[pc];
        if (tid < 256) {
            int yq = (sub << 2) + (tid >> 6);
            int xq = tid & 63;
            float acc = 0.0f;
            for (int dy = -1; dy <= 1; ++dy) {
                int yy = yq + dy; if (yy < 0 || yy > 63) continue;
                for (int dx = -1; dx <= 1; ++dx) {
                    int xc = xq + dx; if (xc < 0 || xc > 63) continue;
                    float4 o4 = ((const float4*)o_buf)[(pb << 12) + (yy << 6) + xc];
                    acc += w0 * o4.x + w1 * o4.y + w2 * o4.z + w3 * o4.w + bbp;
                }
            }
            blur_buf[(bc << 12) + (yq << 6) + xq] = acc * (1.0f / 9.0f);
        }
    }
    grid_bar(cnt, 18);

    // =====================================================================
    // Stage 4: edge enhance + spatial conv + 1x1 combine + dry/wet mix.
    // Block owns 64 px; thread = (px 0..63, cout 0..3); tid<256 active.
    // =====================================================================
    if (tid < 256) {
        const int co = tid >> 6;
        const int pl = (blk << 6) + (tid & 63);
        const int fb_ = pl >> 12, ss = pl & 4095;
        const int y = ss >> 6, xx0 = ss & 63;

        float spat[8];
        #pragma unroll
        for (int j = 0; j < 8; ++j) spat[j] = s_sb[j];
        for (int dy = -1; dy <= 1; ++dy) {
            int yy = y + dy;
            if (yy < 0 || yy > 63) continue;
            for (int dx = -1; dx <= 1; ++dx) {
                int xc = xx0 + dx;
                if (xc < 0 || xc > 63) continue;
                int ky = dy + 1, kx = dx + 1;
                #pragma unroll
                for (int ci = 0; ci < 4; ++ci) {
                    float xv = x[((fb_ * 4 + ci) << 12) + (yy << 6) + xc];
                    #pragma unroll
                    for (int j = 0; j < 8; ++j)
                        spat[j] += s_sw[((j * 4 + ci) * 3 + ky) * 3 + kx] * xv;
                }
            }
        }
        float wetF[4];
        #pragma unroll
        for (int c = 0; c < 4; ++c) {
            const float* plb = blur_buf + ((fb_ * 4 + c) << 12);
            float center = plb[ss];
            float sum9 = 0.0f;
            for (int dy = -1; dy <= 1; ++dy) {
                int yy = y + dy;
                if (yy < 0 || yy > 63) continue;
                for (int dx = -1; dx <= 1; ++dx) {
                    int xc = xx0 + dx;
                    if (xc < 0 || xc > 63) continue;
                    sum9 += plb[(yy << 6) + xc];
                }
            }
            wetF[c] = center + 0.04f * (9.0f * center - sum9);
        }
        float pv = s_ob[co];
        #pragma unroll
        for (int j = 0; j < 8; ++j) pv += s_ow[co * 12 + j] * spat[j];
        #pragma unroll
        for (int c = 0; c < 4; ++c) pv += s_ow[co * 12 + 8 + c] * wetF[c];
        float xc0 = x[((fb_ * 4 + co) << 12) + ss];
        out[((fb_ * 4 + co) << 12) + ss] = 0.7f * xc0 + 0.3f * pv;
    }
}

// ---------------------------------------------------------------------------
extern "C" void kernel_launch(void* const* d_in, const int* in_sizes, int n_in,
                              void* d_out, int out_size, void* d_ws, size_t ws_size,
                              hipStream_t stream)
{
    (void)in_sizes; (void)n_in; (void)out_size; (void)ws_size;
    const float* x    = (const float*)d_in[0];
    const float* rw   = (const float*)d_in[1];
    const float* dl   = (const float*)d_in[2];
    // d_in[3] diffusion_strength: unused by reference
    const float* sw   = (const float*)d_in[4];
    const float* sb   = (const float*)d_in[5];
    const float* fbw  = (const float*)d_in[6];
    const float* fbb  = (const float*)d_in[7];
    const float* d1w  = (const float*)d_in[8];
    const float* d1b  = (const float*)d_in[9];
    const float* d2w  = (const float*)d_in[10];
    const float* d2b  = (const float*)d_in[11];
    const float* aiw  = (const float*)d_in[12];
    const float* aib  = (const float*)d_in[13];
    const float* aow  = (const float*)d_in[14];
    const float* aob  = (const float*)d_in[15];
    const float* ow   = (const float*)d_in[16];
    const float* ob   = (const float*)d_in[17];
    float* out = (float*)d_out;

    // ws layout: wet 256KB | fbA 256KB (reused as o) | fbB 256KB (reused as blur) | cnt 1.3KB
    float* ws_wet  = (float*)d_ws;
    float* fbA     = ws_wet + 65536;
    float* fbB     = fbA + 65536;
    unsigned* cnt  = (unsigned*)(fbB + 65536);
    float* o_buf    = fbA;      // dead after reverb
    float* blur_buf = fbB;      // dead after reverb

    fused_kernel<<<GRID, 512, 0, stream>>>(
        x, rw, dl, fbw, fbb, d1w, d1b, d2w, d2b,
        aiw, aib, aow, aob, sw, sb, ow, ob,
        (float4*)fbA, (float4*)fbB, (float4*)ws_wet, o_buf, blur_buf, cnt, out);
}

// Round 8
// 289.393 us; speedup vs baseline: 1.8500x; 1.8500x over previous
//
#include <hip/hip_runtime.h>

#define LOG2E 1.4426950408889634f
#define GRID 256
#define RVB 32            // reverb subset: blocks 0..31 (round-5-proven layout)
#define MAGIC 0x13579BDFu

// fast sigmoid: rcp approx ~1e-6 rel; tolerance headroom is ~250x
__device__ __forceinline__ float fsig(float z) {
    return __builtin_amdgcn_rcpf(1.0f + exp2f(-z * LOG2E));
}

// ---------------------------------------------------------------------------
// Device-scope barrier v2: arrive (one RMW per block) + release flag; waiters
// spin on READ-ONLY agent-scope loads (no RMW ping-pong). Arrive word and
// release word on separate cachelines. Slot j: arrive cnt[16+32j], release
// cnt[16+32j+16]. Subset barriers: only `target` blocks need participate.
// SLP must be a compile-time constant (s_sleep takes an immediate).
// ---------------------------------------------------------------------------
template <int SLP>
__device__ __forceinline__ void grid_bar(unsigned* cnt, int slot, unsigned target) {
    __syncthreads();
    if (threadIdx.x == 0) {
        __threadfence();
        unsigned* arr = &cnt[16 + slot * 32];
        unsigned* rel = arr + 16;
        unsigned old = atomicAdd(arr, 1u);
        if (old == target - 1u) {
            atomicExch(rel, MAGIC);
        } else {
            while (__hip_atomic_load(rel, __ATOMIC_RELAXED, __HIP_MEMORY_SCOPE_AGENT) != MAGIC)
                __builtin_amdgcn_s_sleep(SLP);
        }
        __threadfence();
    }
    __syncthreads();
}

// ---------------------------------------------------------------------------
// conv3x3(roll(fb)*fade) + damping MLP at one pixel, fb in global (L2).
// ---------------------------------------------------------------------------
__device__ __forceinline__ void conv_damp(
    const float4* __restrict__ src, int yq, int xq, int ys, int xs,
    const float* fe, const float4 wr[9][4],
    const float4 d1w0, const float4 d1w1, const float2 d1b, const float4 d2p[4],
    float rv[4])
{
    float r[4] = { d2p[0].w, d2p[1].w, d2p[2].w, d2p[3].w };   // conv bias (fbb)
    #pragma unroll
    for (int a = 0; a < 3; ++a) {
        int yy = yq - 1 + a;
        float fy = fe[yy + 1];                       // 0 outside image -> zero pad
        const float4* rowp = src + (((yy - ys) & 63) << 6);
        #pragma unroll
        for (int qq = 0; qq < 3; ++qq) {
            int xt = xq - 1 + qq;
            float f = fy * fe[xt + 1];
            float4 v = rowp[(xt - xs) & 63];
            float s0 = v.x * f, s1 = v.y * f, s2 = v.z * f, s3 = v.w * f;
            #pragma unroll
            for (int co = 0; co < 4; ++co) {
                float4 w = wr[a * 3 + qq][co];
                r[co] = fmaf(w.x, s0, fmaf(w.y, s1, fmaf(w.z, s2, fmaf(w.w, s3, r[co]))));
            }
        }
    }
    float z0 = fmaf(d1w0.x, r[0], fmaf(d1w0.y, r[1], fmaf(d1w0.z, r[2], fmaf(d1w0.w, r[3], d1b.x))));
    float z1 = fmaf(d1w1.x, r[0], fmaf(d1w1.y, r[1], fmaf(d1w1.z, r[2], fmaf(d1w1.w, r[3], d1b.y))));
    float h0 = z0 * fsig(z0);
    float h1 = z1 * fsig(z1);
    #pragma unroll
    for (int c = 0; c < 4; ++c) {
        float dm = fsig(fmaf(d2p[c].x, h0, fmaf(d2p[c].y, h1, d2p[c].z)));
        rv[c] = r[c] * dm;
    }
}

// ---------------------------------------------------------------------------
// Single fused kernel: reverb (blocks 0..31, subset barriers) -> attention ->
// proj+blur -> final (all 256 blocks). Boot flag replaces init launch.
// ---------------------------------------------------------------------------
__global__ __launch_bounds__(512) void fused_kernel(
    const float* __restrict__ x, const float* __restrict__ rw, const float* __restrict__ dl,
    const float* __restrict__ fbw, const float* __restrict__ fbb,
    const float* __restrict__ d1wg, const float* __restrict__ d1bg,
    const float* __restrict__ d2wg, const float* __restrict__ d2bg,
    const float* __restrict__ aiw, const float* __restrict__ aib,
    const float* __restrict__ aow, const float* __restrict__ aob,
    const float* __restrict__ swg, const float* __restrict__ sbg,
    const float* __restrict__ owg, const float* __restrict__ obg,
    float4* __restrict__ fbA, float4* __restrict__ fbB,
    float4* __restrict__ ws_wet, float* __restrict__ o_buf, float* __restrict__ blur_buf,
    unsigned* __restrict__ cnt, float* __restrict__ out)
{
    __shared__ float4 kvs4[2048];     // 32 KB: (k,v) pairs for 4096 keys
    __shared__ float2 part[2048];     // 16 KB: [kg][row_local]
    __shared__ float fe[66];
    __shared__ float4 wvsL[36];
    __shared__ float s_rw[16], s_dl[16];
    __shared__ float4 s_mlp[7];
    __shared__ float s_sw[288], s_ow[48], s_sb[8], s_ob[4];
    __shared__ float redmx[8], redmn[8];

    const int tid = threadIdx.x;
    const int blk = blockIdx.x;

    // ---- stage LDS statics (all blocks) ----
    if (tid < 66) {
        float f = 0.0f;
        if (tid >= 1 && tid <= 64) {
            int j = tid - 1;
            f = 1.0f;
            if (j < 4) f = 0.6f + (0.4f / 3.0f) * j;
            else if (j >= 60) f = 0.6f + (0.4f / 3.0f) * (63 - j);
        }
        fe[tid] = f;
    }
    if (tid >= 128 && tid < 164) {
        int t2 = tid - 128, n = t2 >> 2, co = t2 & 3;
        wvsL[t2] = make_float4(fbw[(co * 4 + 0) * 9 + n], fbw[(co * 4 + 1) * 9 + n],
                               fbw[(co * 4 + 2) * 9 + n], fbw[(co * 4 + 3) * 9 + n]);
    }
    if (tid >= 192 && tid < 208) s_rw[tid - 192] = rw[tid - 192];
    if (tid >= 224 && tid < 240) s_dl[tid - 224] = dl[tid - 224];
    if (tid == 256) {
        s_mlp[0] = make_float4(d1wg[0], d1wg[1], d1wg[2], d1wg[3]);
        s_mlp[1] = make_float4(d1wg[4], d1wg[5], d1wg[6], d1wg[7]);
        s_mlp[2] = make_float4(d1bg[0], d1bg[1], 0.0f, 0.0f);
        for (int c = 0; c < 4; ++c)
            s_mlp[3 + c] = make_float4(d2wg[c * 2], d2wg[c * 2 + 1], d2bg[c], fbb[c]);
    }
    if (tid >= 336 && tid < 384) s_ow[tid - 336] = owg[tid - 336];
    if (tid >= 384 && tid < 392) s_sb[tid - 384] = sbg[tid - 384];
    if (tid >= 392 && tid < 396) s_ob[tid - 392] = obg[tid - 392];
    for (int j = tid; j < 288; j += 512) s_sw[j] = swg[j];

    // ---- boot: block 0 zeros barrier slots (19 slots x 32 words), raises flag ----
    if (blk == 0) {
        for (int i = tid; i < 19 * 32; i += 512) cnt[16 + i] = 0u;
        __syncthreads();                       // zeroing + LDS statics done
        if (tid == 0) { __threadfence(); atomicExch(&cnt[0], MAGIC); }
    } else {
        __syncthreads();                       // LDS statics done
        if (tid == 0) {
            while (__hip_atomic_load(&cnt[0], __ATOMIC_RELAXED, __HIP_MEMORY_SCOPE_AGENT) != MAGIC)
                __builtin_amdgcn_s_sleep(2);
        }
        __syncthreads();
    }

    // =====================================================================
    // Stage 1: reverb, blocks 0..31 only (round-5 layout: block owns 8 rows
    // of one batch, 1 px/thread, 512 workers). Subset barriers target=32.
    // Blocks 32..255 skip to the stage-2 entry barrier (slot 16, target 256).
    // =====================================================================
    if (blk < RVB) {
        const int b  = blk >> 3;
        const int y0 = ((blk & 7) << 3) + (tid >> 6);
        const int xx = tid & 63;
        const int s_ = (y0 << 6) + xx;
        float4* A = fbA + (b << 12);
        float4* B = fbB + (b << 12);

        float4 wr[9][4];
        #pragma unroll
        for (int n = 0; n < 9; ++n)
            #pragma unroll
            for (int co = 0; co < 4; ++co) wr[n][co] = wvsL[n * 4 + co];
        const float4 d1w0 = s_mlp[0], d1w1 = s_mlp[1];
        const float2 d1b = make_float2(s_mlp[2].x, s_mlp[2].y);
        float4 d2p[4] = { s_mlp[3], s_mlp[4], s_mlp[5], s_mlp[6] };

        float4 fbv;
        fbv.x = 0.1f * x[((b * 4 + 0) << 12) + s_];
        fbv.y = 0.1f * x[((b * 4 + 1) << 12) + s_];
        fbv.z = 0.1f * x[((b * 4 + 2) << 12) + s_];
        fbv.w = 0.1f * x[((b * 4 + 3) << 12) + s_];
        A[s_] = fbv;
        grid_bar<1>(cnt, 0, RVB);

        float acc0 = 0.0f, acc1 = 0.0f, acc2 = 0.0f, acc3 = 0.0f;
        float decay = 1.0f;
        for (int i = 0; i < 16; ++i) {
            const float4* src = (i & 1) ? B : A;
            float4* dst = (i & 1) ? A : B;
            float d = s_dl[i];
            int ys  = ((int)(3.0f * d)) & 63;
            int xs  = ((int)(6.0f * d)) & 63;
            int ys2 = ((int)(1.5f * d)) & 63;
            int xs2 = ((int)(3.0f * d)) & 63;
            float wgt = fsig(s_rw[i]) * decay * 3.0f;

            float rv[4];
            conv_damp(src, y0, xx, ys, xs, fe, wr, d1w0, d1w1, d1b, d2p, rv);
            acc0 = fmaf(rv[0], wgt, acc0);
            acc1 = fmaf(rv[1], wgt, acc1);
            acc2 = fmaf(rv[2], wgt, acc2);
            acc3 = fmaf(rv[3], wgt, acc3);
            float4 fnew = make_float4(fbv.x + 0.24f * rv[0], fbv.y + 0.24f * rv[1],
                                      fbv.z + 0.24f * rv[2], fbv.w + 0.24f * rv[3]);
            if (i > 0) {
                int yr = (y0 - ys2) & 63, xr = (xx - xs2) & 63;
                float rvr[4];
                conv_damp(src, yr, xr, ys, xs, fe, wr, d1w0, d1w1, d1b, d2p, rvr);
                float4 fr = src[(yr << 6) + xr];
                float f = 0.08f * fe[y0 + 1] * fe[xx + 1];
                fnew.x = fmaf(f, fmaf(0.24f, rvr[0], fr.x), fnew.x);
                fnew.y = fmaf(f, fmaf(0.24f, rvr[1], fr.y), fnew.y);
                fnew.z = fmaf(f, fmaf(0.24f, rvr[2], fr.z), fnew.z);
                fnew.w = fmaf(f, fmaf(0.24f, rvr[3], fr.w), fnew.w);
            }
            dst[s_] = fnew;
            fbv = fnew;
            decay *= 0.8f;
            if (i < 15) grid_bar<1>(cnt, 1 + i, RVB);
        }
        ws_wet[(b << 12) + s_] = make_float4(acc0, acc1, acc2, acc3);
        grid_bar<1>(cnt, 16, GRID);
    } else {
        grid_bar<8>(cnt, 16, GRID);    // coarse sleep: long wait, few loads
    }

    // =====================================================================
    // Stage 2: attention (head_dim=1). Block = (b,h, 256-row chunk).
    // 512 thr = 64 row-slots (4 rows each) x 8 key-groups (512 keys each).
    // =====================================================================
    {
        const int bh = blk >> 4;
        const int ab = bh >> 2, ah = bh & 3;
        const int qc = blk & 15;

        float wq[4], wk[4], wv[4];
        #pragma unroll
        for (int c = 0; c < 4; ++c) {
            wq[c] = aiw[ah * 4 + c];
            wk[c] = aiw[(4 + ah) * 4 + c];
            wv[c] = aiw[(8 + ah) * 4 + c];
        }
        const float bq = aib[ah], bk = aib[4 + ah], bv = aib[8 + ah];

        float2* kvs = (float2*)kvs4;
        float lmax = -1e30f, lmin = 1e30f;
        for (int s = tid; s < 4096; s += 512) {
            float4 w4 = ws_wet[(ab << 12) + s];
            float k = wk[0] * w4.x + wk[1] * w4.y + wk[2] * w4.z + wk[3] * w4.w + bk;
            float v = wv[0] * w4.x + wv[1] * w4.y + wv[2] * w4.z + wv[3] * w4.w + bv;
            kvs[s] = make_float2(k, v);
            lmax = fmaxf(lmax, k); lmin = fminf(lmin, k);
        }
        #pragma unroll
        for (int off = 32; off > 0; off >>= 1) {
            lmax = fmaxf(lmax, __shfl_xor(lmax, off));
            lmin = fminf(lmin, __shfl_xor(lmin, off));
        }
        if ((tid & 63) == 0) { redmx[tid >> 6] = lmax; redmn[tid >> 6] = lmin; }
        __syncthreads();
        float kmax = redmx[0], kmin = redmn[0];
        #pragma unroll
        for (int w = 1; w < 8; ++w) { kmax = fmaxf(kmax, redmx[w]); kmin = fminf(kmin, redmn[w]); }

        const int rs = tid & 63;
        const int kg = tid >> 6;
        float qL[4], mL[4];
        #pragma unroll
        for (int rr = 0; rr < 4; ++rr) {
            int row = (qc << 8) + (rs << 2) + rr;
            float4 w4 = ws_wet[(ab << 12) + row];
            float q = wq[0] * w4.x + wq[1] * w4.y + wq[2] * w4.z + wq[3] * w4.w + bq;
            float m = (q >= 0.0f) ? q * kmax : q * kmin;   // exact row max (hd=1)
            qL[rr] = q * LOG2E; mL[rr] = m * LOG2E;
        }

        float den[4] = {0, 0, 0, 0}, num[4] = {0, 0, 0, 0};
        const int j0 = kg << 8;        // 256 float4 = 512 keys per group
        #pragma unroll 2
        for (int j = j0; j < j0 + 256; ++j) {
            float4 t = kvs4[j];
            #pragma unroll
            for (int rr = 0; rr < 4; ++rr) {
                float e0 = exp2f(fmaf(qL[rr], t.x, -mL[rr]));
                float e1 = exp2f(fmaf(qL[rr], t.z, -mL[rr]));
                den[rr] += e0 + e1;
                num[rr] = fmaf(e0, t.y, fmaf(e1, t.w, num[rr]));
            }
        }
        #pragma unroll
        for (int rr = 0; rr < 4; ++rr)
            part[(kg << 8) + (rs << 2) + rr] = make_float2(den[rr], num[rr]);
        __syncthreads();
        if (tid < 256) {
            float dd = 0.0f, nn = 0.0f;
            #pragma unroll
            for (int g = 0; g < 8; ++g) {
                float2 pp = part[(g << 8) + tid];
                dd += pp.x; nn += pp.y;
            }
            int row = (qc << 8) + tid;
            o_buf[(((ab << 12) + row) << 2) + ah] = nn * __builtin_amdgcn_rcpf(dd);
        }
    }
    grid_bar<2>(cnt, 17, GRID);

    // =====================================================================
    // Stage 3: attn out-projection + 3x3 box blur (on the fly, zero pad).
    // Block = (plane bc, 4-row slab). Threads 0..255: 1 px each.
    // =====================================================================
    {
        const int bc = blk >> 4;
        const int sub = blk & 15;
        const int pb = bc >> 2, pc = bc & 3;
        const float w0 = aow[pc * 4], w1 = aow[pc * 4 + 1],
                    w2 = aow[pc * 4 + 2], w3 = aow[pc * 4 + 3];
        const float bbp = aob[pc];
        if (tid < 256) {
            int yq = (sub << 2) + (tid >> 6);
            int xq = tid & 63;
            float acc = 0.0f;
            for (int dy = -1; dy <= 1; ++dy) {
                int yy = yq + dy; if (yy < 0 || yy > 63) continue;
                for (int dx = -1; dx <= 1; ++dx) {
                    int xc = xq + dx; if (xc < 0 || xc > 63) continue;
                    float4 o4 = ((const float4*)o_buf)[(pb << 12) + (yy << 6) + xc];
                    acc += w0 * o4.x + w1 * o4.y + w2 * o4.z + w3 * o4.w + bbp;
                }
            }
            blur_buf[(bc << 12) + (yq << 6) + xq] = acc * (1.0f / 9.0f);
        }
    }
    grid_bar<2>(cnt, 18, GRID);

    // =====================================================================
    // Stage 4: edge enhance + spatial conv + 1x1 combine + dry/wet mix.
    // Block owns 64 px; thread = (px 0..63, cout 0..3); tid<256 active.
    // =====================================================================
    if (tid < 256) {
        const int co = tid >> 6;
        const int pl = (blk << 6) + (tid & 63);
        const int fb_ = pl >> 12, ss = pl & 4095;
        const int y = ss >> 6, xx0 = ss & 63;

        float spat[8];
        #pragma unroll
        for (int j = 0; j < 8; ++j) spat[j] = s_sb[j];
        for (int dy = -1; dy <= 1; ++dy) {
            int yy = y + dy;
            if (yy < 0 || yy > 63) continue;
            for (int dx = -1; dx <= 1; ++dx) {
                int xc = xx0 + dx;
                if (xc < 0 || xc > 63) continue;
                int ky = dy + 1, kx = dx + 1;
                #pragma unroll
                for (int ci = 0; ci < 4; ++ci) {
                    float xv = x[((fb_ * 4 + ci) << 12) + (yy << 6) + xc];
                    #pragma unroll
                    for (int j = 0; j < 8; ++j)
                        spat[j] += s_sw[((j * 4 + ci) * 3 + ky) * 3 + kx] * xv;
                }
            }
        }
        float wetF[4];
        #pragma unroll
        for (int c = 0; c < 4; ++c) {
            const float* plb = blur_buf + ((fb_ * 4 + c) << 12);
            float center = plb[ss];
            float sum9 = 0.0f;
            for (int dy = -1; dy <= 1; ++dy) {
                int yy = y + dy;
                if (yy < 0 || yy > 63) continue;
                for (int dx = -1; dx <= 1; ++dx) {
                    int xc = xx0 + dx;
                    if (xc < 0 || xc > 63) continue;
                    sum9 += plb[(yy << 6) + xc];
                }
            }
            wetF[c] = center + 0.04f * (9.0f * center - sum9);
        }
        float pv = s_ob[co];
        #pragma unroll
        for (int j = 0; j < 8; ++j) pv += s_ow[co * 12 + j] * spat[j];
        #pragma unroll
        for (int c = 0; c < 4; ++c) pv += s_ow[co * 12 + 8 + c] * wetF[c];
        float xc0 = x[((fb_ * 4 + co) << 12) + ss];
        out[((fb_ * 4 + co) << 12) + ss] = 0.7f * xc0 + 0.3f * pv;
    }
}

// ---------------------------------------------------------------------------
extern "C" void kernel_launch(void* const* d_in, const int* in_sizes, int n_in,
                              void* d_out, int out_size, void* d_ws, size_t ws_size,
                              hipStream_t stream)
{
    (void)in_sizes; (void)n_in; (void)out_size; (void)ws_size;
    const float* x    = (const float*)d_in[0];
    const float* rw   = (const float*)d_in[1];
    const float* dl   = (const float*)d_in[2];
    // d_in[3] diffusion_strength: unused by reference
    const float* sw   = (const float*)d_in[4];
    const float* sb   = (const float*)d_in[5];
    const float* fbw  = (const float*)d_in[6];
    const float* fbb  = (const float*)d_in[7];
    const float* d1w  = (const float*)d_in[8];
    const float* d1b  = (const float*)d_in[9];
    const float* d2w  = (const float*)d_in[10];
    const float* d2b  = (const float*)d_in[11];
    const float* aiw  = (const float*)d_in[12];
    const float* aib  = (const float*)d_in[13];
    const float* aow  = (const float*)d_in[14];
    const float* aob  = (const float*)d_in[15];
    const float* ow   = (const float*)d_in[16];
    const float* ob   = (const float*)d_in[17];
    float* out = (float*)d_out;

    // ws layout: wet 256KB | fbA 256KB (reused as o) | fbB 256KB (reused as blur) | cnt ~2.5KB
    float* ws_wet  = (float*)d_ws;
    float* fbA     = ws_wet + 65536;
    float* fbB     = fbA + 65536;
    unsigned* cnt  = (unsigned*)(fbB + 65536);
    float* o_buf    = fbA;      // dead after reverb
    float* blur_buf = fbB;      // dead after reverb

    fused_kernel<<<GRID, 512, 0, stream>>>(
        x, rw, dl, fbw, fbb, d1w, d1b, d2w, d2b,
        aiw, aib, aow, aob, sw, sb, ow, ob,
        (float4*)fbA, (float4*)fbB, (float4*)ws_wet, o_buf, blur_buf, cnt, out);
}